// Round 17
// baseline (276.012 us; speedup 1.0000x reference)
//
#include <hip/hip_runtime.h>
#include <hip/hip_bf16.h>
#include <hip/hip_cooperative_groups.h>

namespace cg = cooperative_groups;

#define B_ 2
#define C_ 256
#define S_ 4096
#define NH 8
#define HD 32
#define EPSV 1e-5f
// QSCALE * log2(e): scores computed in log2 units so softmax uses exp2
#define QSC2 0.25503487942324256f

typedef __bf16 bf16_t;
typedef bf16_t bf16x8 __attribute__((ext_vector_type(8)));
typedef float f32x4 __attribute__((ext_vector_type(4)));
typedef float f32x16 __attribute__((ext_vector_type(16)));
typedef int i32x2 __attribute__((ext_vector_type(2)));
typedef __hip_bfloat16 hbf;

__device__ inline unsigned cvtpk_bf16(float a, float b) {
  unsigned r;
  asm("v_cvt_pk_bf16_f32 %0, %1, %2" : "=v"(r) : "v"(a), "v"(b));
  return r;
}

// raw hardware exp2 (v_exp_f32): scores are tiny, no range handling needed
#if __has_builtin(__builtin_amdgcn_exp2f)
#define EXP2R(x) __builtin_amdgcn_exp2f(x)
#else
#define EXP2R(x) exp2f(x)
#endif

// ---------------- fused prep + groupnorm + qkv (cooperative, 3 phases) ----------------
// Phase 1: blocks [0,96) qkv_w->frag, [96,128) proj_w->frag, [128,640) gn partial sums.
// Phase 2: blocks [0,512) gn apply (normalize + fragment-major transpose store).
// Phase 3: all 768 blocks: qkv GEMM (LDS-free, fragment-major), 256 thr = 4 waves.
// fragment-major weights: wf[o/32][c/16][o%32][16]; xn[b][s/32][c/16][s%32][16].
__global__ __launch_bounds__(256) void fused_pre(const float* __restrict__ qkv_w,
                                                 const float* __restrict__ proj_w,
                                                 const float* __restrict__ x,
                                                 const float* __restrict__ gn_w,
                                                 const float* __restrict__ gn_b,
                                                 hbf* __restrict__ qkv_wf, hbf* __restrict__ proj_wf,
                                                 float* __restrict__ stats, hbf* __restrict__ xn,
                                                 const float* __restrict__ qkv_b,
                                                 hbf* __restrict__ qbuf, hbf* __restrict__ kg,
                                                 hbf* __restrict__ vg) {
  __shared__ float red[2][4];
  int blk = blockIdx.x;
  int tid = threadIdx.x;
  // ---- phase 1 ----
  if (blk < 128) {
    const float* src = (blk < 96) ? qkv_w : proj_w;
    hbf* dst = (blk < 96) ? qkv_wf : proj_wf;
    int i = (blk < 96 ? blk : blk - 96) * 256 + tid;
    int o = i >> 5, c8 = (i & 31) * 8;
    alignas(16) hbf tmp[8];
#pragma unroll
    for (int j = 0; j < 8; j++) tmp[j] = __float2bfloat16(src[(size_t)o * C_ + c8 + j]);
    *(uint4*)&dst[(((size_t)(o >> 5) * 16) + (c8 >> 4)) * 512 + (o & 31) * 16 + (c8 & 15)] = *(uint4*)tmp;
  } else if (blk < 640) {
    int sb = blk - 128;
    int bg = sb >> 3, chunk = sb & 7;
    const float4* xp4 = (const float4*)(x + (size_t)bg * 8 * S_);
    float sum = 0.f, sumsq = 0.f;
#pragma unroll
    for (int p = 0; p < 4; p++) {
      int i = tid + p * 256;                  // 1024 float4s: 8 ch x 128
      int ch = i >> 7, s4 = i & 127;
      float4 v = xp4[ch * (S_ >> 2) + chunk * 128 + s4];
      sum += v.x + v.y + v.z + v.w;
      sumsq += v.x * v.x + v.y * v.y + v.z * v.z + v.w * v.w;
    }
#pragma unroll
    for (int off = 32; off > 0; off >>= 1) {
      sum += __shfl_down(sum, off);
      sumsq += __shfl_down(sumsq, off);
    }
    int wid = tid >> 6;
    if ((tid & 63) == 0) { red[0][wid] = sum; red[1][wid] = sumsq; }
    __syncthreads();
    if (tid == 0) {
      stats[sb * 2 + 0] = red[0][0] + red[0][1] + red[0][2] + red[0][3];
      stats[sb * 2 + 1] = red[1][0] + red[1][1] + red[1][2] + red[1][3];
    }
  }
  cg::this_grid().sync();
  // ---- phase 2: gn apply ----
  if (blk < 512) {
    int bg = blk >> 3, chunk = blk & 7;
    int b = bg >> 5, g = bg & 31;
    const float* xp = x + (size_t)bg * 8 * S_;
    float sum = 0.f, sumsq = 0.f;
#pragma unroll
    for (int k = 0; k < 8; k++) {             // fixed order: deterministic
      sum += stats[(bg * 8 + k) * 2 + 0];
      sumsq += stats[(bg * 8 + k) * 2 + 1];
    }
    const float inv_n = 1.f / (8 * S_);
    float mean = sum * inv_n;
    float rstd = rsqrtf(fmaxf(sumsq * inv_n - mean * mean, 0.f) + EPSV);
    float scv[8], shv[8];
#pragma unroll
    for (int c = 0; c < 8; c++) {
      scv[c] = gn_w[g * 8 + c] * rstd;
      shv[c] = gn_b[g * 8 + c] - mean * scv[c];
    }
#pragma unroll
    for (int p = 0; p < 2; p++) {
      int s = chunk * 512 + p * 256 + tid;
      alignas(16) hbf tmp[8];
#pragma unroll
      for (int c = 0; c < 8; c++)
        tmp[c] = __float2bfloat16(xp[(size_t)c * S_ + s] * scv[c] + shv[c]);
      *(uint4*)&xn[(((size_t)b * (S_ >> 5) + (s >> 5)) * 16 + (g >> 1)) * 512 + (s & 31) * 16 + (g & 1) * 8] =
          *(uint4*)tmp;
    }
  }
  cg::this_grid().sync();
  // ---- phase 3: qkv GEMM (4 waves: 2 s-sub x 2 o-sub; wave = 32 s x 64 o) ----
  {
    int sx = blk & 63;
    int r = blk >> 6;                 // 0..11
    int bt = (r >= 6) ? 1 : 0;
    int oy = r - bt * 6;
    int m0 = sx * 64;
    int n0 = oy * 128;
    int lane = tid & 63, w = tid >> 6;
    int wq = w & 1, wo = w >> 1;
    int l31 = lane & 31, hi = lane >> 5;
    const int loff = l31 * 16 + hi * 8;
    const hbf* ap = xn + ((size_t)bt * (S_ >> 5) + (m0 >> 5) + wq) * 8192;
    int oc0 = n0 + wo * 64;
    const hbf* bp0 = qkv_wf + (size_t)(oc0 >> 5) * 8192;
    const hbf* bp1 = bp0 + 8192;
    f32x16 acc0 = {0.f,0.f,0.f,0.f,0.f,0.f,0.f,0.f,0.f,0.f,0.f,0.f,0.f,0.f,0.f,0.f};
    f32x16 acc1 = acc0;
#pragma unroll 4
    for (int ks = 0; ks < 16; ++ks) {
      bf16x8 af = *(const bf16x8*)(ap + ks * 512 + loff);
      bf16x8 b0 = *(const bf16x8*)(bp0 + ks * 512 + loff);
      bf16x8 b1 = *(const bf16x8*)(bp1 + ks * 512 + loff);
      acc0 = __builtin_amdgcn_mfma_f32_32x32x16_bf16(af, b0, acc0, 0, 0, 0);
      acc1 = __builtin_amdgcn_mfma_f32_32x32x16_bf16(af, b1, acc1, 0, 0, 0);
    }
    int s_base = m0 + wq * 32;
#pragma unroll
    for (int ct = 0; ct < 2; ++ct) {
      f32x16 a = ct ? acc1 : acc0;
      int oc = oc0 + ct * 32;         // uniform per col-tile
      int o = oc + l31;
      float bs = qkv_b[o];
      if (oc < 256) {
#pragma unroll
        for (int rr = 0; rr < 16; rr++) {
          int s = s_base + (rr & 3) + 8 * (rr >> 2) + 4 * hi;
          qbuf[((size_t)bt * S_ + s) * C_ + o] = __float2bfloat16((a[rr] + bs) * QSC2);
        }
      } else if (oc < 512) {
        int hh = (oc - 256) >> 5;
        const size_t khead = (size_t)(bt * NH + hh) * (S_ >> 5);
#pragma unroll
        for (int rr = 0; rr < 16; rr++) {
          int s = s_base + (rr & 3) + 8 * (rr >> 2) + 4 * hi;
          kg[(khead + (s >> 5)) * 1024 + (l31 >> 4) * 512 + (s & 31) * 16 + (l31 & 15)] =
              __float2bfloat16(a[rr] + bs);
        }
      } else {
        int hh = (oc - 512) >> 5;
        const size_t vhead = (size_t)(bt * NH + hh) * (S_ >> 4);
#pragma unroll
        for (int rr = 0; rr < 16; rr++) {
          int s = s_base + (rr & 3) + 8 * (rr >> 2) + 4 * hi;
          vg[(vhead + (s >> 4)) * 512 + l31 * 16 + (s & 15)] = __float2bfloat16(a[rr] + bs);
        }
      }
    }
  }
}

// softmax numerator + P relayout + PV + l (ones-MFMA) for ONE 32-t tile
__device__ inline void softmax_pv(f32x16 sc, bf16x8 va0, bf16x8 va1, bf16x8 ones,
                                  f32x16& o_acc, f32x16& l_acc) {
#pragma unroll
  for (int i = 0; i < 16; i++) sc[i] = EXP2R(sc[i]);
#pragma unroll
  for (int kb = 0; kb < 2; kb++) {
    unsigned a0 = cvtpk_bf16(sc[kb * 8 + 0], sc[kb * 8 + 1]);
    unsigned b0 = cvtpk_bf16(sc[kb * 8 + 2], sc[kb * 8 + 3]);
    unsigned a1 = cvtpk_bf16(sc[kb * 8 + 4], sc[kb * 8 + 5]);
    unsigned b1 = cvtpk_bf16(sc[kb * 8 + 6], sc[kb * 8 + 7]);
    i32x2 ra = __builtin_amdgcn_permlane32_swap((int)a0, (int)a1, false, false);
    i32x2 rb = __builtin_amdgcn_permlane32_swap((int)b0, (int)b1, false, false);
    union { unsigned u[4]; bf16x8 v; } pf;
    pf.u[0] = (unsigned)ra[0]; pf.u[1] = (unsigned)rb[0];
    pf.u[2] = (unsigned)ra[1]; pf.u[3] = (unsigned)rb[1];
    // l on the MFMA pipe: D[i][q] += sum_k P[k][q] (rows identical)
    l_acc = __builtin_amdgcn_mfma_f32_32x32x16_bf16(ones, pf.v, l_acc, 0, 0, 0);
    o_acc = __builtin_amdgcn_mfma_f32_32x32x16_bf16(kb ? va1 : va0, pf.v, o_acc, 0, 0, 0);
  }
}

// ---------------- Flash attention v15: ping-pong pipeline + l via ones-MFMA ----------------
// Block: 512 threads, 8 waves = 2 q-subtiles(32 rows) x 4 t-quarters(1024 t each); 1024 blocks.
// LDS-free main loop; K/V fragment-major. Pipeline: QK[tile it] MFMAs issue before the
// exp2/cvt/perm VALU block of tile it-1. l accumulated by mfma(ones, P) on the MFMA pipe
// (frees the 15-add serial VALU tree; MFMA pipe has headroom at 27%).
__global__ __launch_bounds__(512, 4) void attn_kernel(const hbf* __restrict__ qbuf, const hbf* __restrict__ kg,
                                                      const hbf* __restrict__ vg, hbf* __restrict__ attn_t) {
  int bid = blockIdx.x;
  int xcd = bid & 7, idx = bid >> 3;       // 128 blocks per XCD
  int combo = (xcd << 1) | (idx >> 6);     // 16 (bt,h) combos; 2 per XCD
  int bt = combo >> 3, h = combo & 7;
  int s0 = (idx & 63) << 6;                // 64 q-blocks of 64
  int tid = threadIdx.x, lane = tid & 63, w = tid >> 6;
  int wq = w & 1, wt = w >> 1;
  int l31 = lane & 31, hi = lane >> 5;
  const int loff = (l31 << 4) + (hi << 3);
  int qrow = s0 + wq * 32 + l31;
  bf16x8 qf0 = *(const bf16x8*)&qbuf[((size_t)bt * S_ + qrow) * C_ + h * HD + hi * 8];
  bf16x8 qf1 = *(const bf16x8*)&qbuf[((size_t)bt * S_ + qrow) * C_ + h * HD + 16 + hi * 8];
  bf16x8 ones;
#pragma unroll
  for (int i = 0; i < 8; i++) ones[i] = (bf16_t)1.0f;
  f32x16 o_acc = {0.f,0.f,0.f,0.f,0.f,0.f,0.f,0.f,0.f,0.f,0.f,0.f,0.f,0.f,0.f,0.f};
  f32x16 l_acc = o_acc;
  const f32x16 z16 = o_acc;
  const int tq0 = wt << 10;
  const hbf* kq = kg + ((size_t)(bt * NH + h) * (S_ >> 5) + (tq0 >> 5)) * 1024;
  const hbf* vq = vg + ((size_t)(bt * NH + h) * (S_ >> 4) + (tq0 >> 4)) * 512;
  // ---- prologue: scores(0); carry kaB = K[1], vaA = V[0] ----
  bf16x8 kaB0 = *(const bf16x8*)(kq + loff);
  bf16x8 kaB1 = *(const bf16x8*)(kq + loff + 512);
  f32x16 scA = __builtin_amdgcn_mfma_f32_32x32x16_bf16(kaB0, qf0, z16, 0, 0, 0);
  scA = __builtin_amdgcn_mfma_f32_32x32x16_bf16(kaB1, qf1, scA, 0, 0, 0);   // scores(0)
  kaB0 = *(const bf16x8*)(kq + loff + 1024);                                 // K[1]
  kaB1 = *(const bf16x8*)(kq + loff + 1536);
  bf16x8 vaA0 = *(const bf16x8*)(vq + loff);                                 // V[0]
  bf16x8 vaA1 = *(const bf16x8*)(vq + loff + 512);
  kq += 2048;   // -> K[2] base
  vq += 1024;   // -> V[1] base
  // ---- steady state: j = 0..14, tiles (2j, 2j+1) ----
  for (int j = 0; j < 15; ++j) {
    bf16x8 vaB0 = *(const bf16x8*)(vq + loff);            // V[2j+1]
    bf16x8 vaB1 = *(const bf16x8*)(vq + loff + 512);
    bf16x8 knA0 = *(const bf16x8*)(kq + loff);            // K[2j+2]
    bf16x8 knA1 = *(const bf16x8*)(kq + loff + 512);
    f32x16 scB = __builtin_amdgcn_mfma_f32_32x32x16_bf16(kaB0, qf0, z16, 0, 0, 0);
    scB = __builtin_amdgcn_mfma_f32_32x32x16_bf16(kaB1, qf1, scB, 0, 0, 0);  // scores(2j+1)
    kaB0 = *(const bf16x8*)(kq + loff + 1024);            // K[2j+3] (reload in place)
    kaB1 = *(const bf16x8*)(kq + loff + 1536);
    softmax_pv(scA, vaA0, vaA1, ones, o_acc, l_acc);      // tile 2j
    vaA0 = *(const bf16x8*)(vq + loff + 1024);            // V[2j+2] (reload in place)
    vaA1 = *(const bf16x8*)(vq + loff + 1536);
    scA = __builtin_amdgcn_mfma_f32_32x32x16_bf16(knA0, qf0, z16, 0, 0, 0);
    scA = __builtin_amdgcn_mfma_f32_32x32x16_bf16(knA1, qf1, scA, 0, 0, 0);  // scores(2j+2)
    softmax_pv(scB, vaB0, vaB1, ones, o_acc, l_acc);      // tile 2j+1
    kq += 2048; vq += 2048;
  }
  // ---- epilogue: tiles 30, 31 ----
  {
    bf16x8 vaB0 = *(const bf16x8*)(vq + loff);
    bf16x8 vaB1 = *(const bf16x8*)(vq + loff + 512);
    f32x16 scB = __builtin_amdgcn_mfma_f32_32x32x16_bf16(kaB0, qf0, z16, 0, 0, 0);
    scB = __builtin_amdgcn_mfma_f32_32x32x16_bf16(kaB1, qf1, scB, 0, 0, 0);  // scores(31)
    softmax_pv(scA, vaA0, vaA1, ones, o_acc, l_acc);      // tile 30
    softmax_pv(scB, vaB0, vaB1, ones, o_acc, l_acc);      // tile 31
  }
  // combine the 4 t-quarter partials (pure sums under fixed-max softmax)
  __shared__ f32x16 ored[6 * 64];
  __shared__ float lred[8 * 64];
  __syncthreads();
  lred[(w << 6) + lane] = l_acc[0];   // full column sum for this quarter (rows & hi-halves identical)
  if (wt > 0) ored[((w - 2) << 6) + lane] = o_acc;
  __syncthreads();
  if (wt == 0) {
    float l_tot = 0.f;
#pragma unroll
    for (int k = 0; k < 4; k++)
      l_tot += lred[((wq + 2 * k) << 6) + l31];   // one term per t-quarter
    f32x16 o = o_acc;
#pragma unroll
    for (int k = 0; k < 3; k++) {
      f32x16 t2 = ored[((wq + 2 * k) << 6) + lane];
#pragma unroll
      for (int i = 0; i < 16; i++) o[i] += t2[i];
    }
    float inv_l = 1.0f / l_tot;
#pragma unroll
    for (int c2 = 0; c2 < 4; c2++) {
      alignas(8) hbf tmp[4];
#pragma unroll
      for (int r = 0; r < 4; r++) tmp[r] = __float2bfloat16(o[c2 * 4 + r] * inv_l);
      *(uint2*)&attn_t[((size_t)bt * S_ + qrow) * C_ + h * HD + c2 * 8 + hi * 4] = *(uint2*)tmp;
    }
  }
}

// ---------------- Proj GEMM v2: LDS-free, fragment-major W, coalesced f32 out ----------------
__global__ __launch_bounds__(256) void proj_gemm(const hbf* __restrict__ attn_t, const hbf* __restrict__ wf,
                                                 const float* __restrict__ bias, const float* __restrict__ x,
                                                 float* __restrict__ out) {
  int bt = blockIdx.z;
  int s_blk = blockIdx.x * 64;
  int o_blk = blockIdx.y * 64;
  int tid = threadIdx.x, lane = tid & 63, w = tid >> 6;
  int wo = w & 1, ws = w >> 1;
  int l31 = lane & 31, hi = lane >> 5;
  const int loff = l31 * 16 + hi * 8;
  int o0 = o_blk + wo * 32;
  int s0 = s_blk + ws * 32;
  const hbf* ap = wf + (size_t)(o0 >> 5) * 8192;               // fragment-major W chunk
  const hbf* bp = attn_t + ((size_t)bt * S_ + s0 + l31) * C_ + hi * 8;  // row s = s0+l31
  f32x16 acc = {0.f,0.f,0.f,0.f,0.f,0.f,0.f,0.f,0.f,0.f,0.f,0.f,0.f,0.f,0.f,0.f};
#pragma unroll 4
  for (int ks = 0; ks < 16; ++ks) {
    bf16x8 af = *(const bf16x8*)(ap + ks * 512 + loff);
    bf16x8 bf_ = *(const bf16x8*)(bp + ks * 16);
    acc = __builtin_amdgcn_mfma_f32_32x32x16_bf16(af, bf_, acc, 0, 0, 0);
  }
  int s = s0 + l31;
#pragma unroll
  for (int r = 0; r < 16; r++) {
    int o = o0 + (r & 3) + 8 * (r >> 2) + 4 * hi;
    size_t idx = ((size_t)bt * C_ + o) * S_ + s;
    out[idx] = acc[r] + bias[o] + x[idx];
  }
}

extern "C" void kernel_launch(void* const* d_in, const int* in_sizes, int n_in,
                              void* d_out, int out_size, void* d_ws, size_t ws_size,
                              hipStream_t stream) {
  const float* x = (const float*)d_in[0];
  const float* gn_w = (const float*)d_in[1];
  const float* gn_b = (const float*)d_in[2];
  const float* qkv_w = (const float*)d_in[3];
  const float* qkv_b = (const float*)d_in[4];
  const float* proj_w = (const float*)d_in[5];
  const float* proj_b = (const float*)d_in[6];
  float* out = (float*)d_out;

  hbf* qkv_wf = (hbf*)d_ws;                                     // 768*256 (fragment-major)
  hbf* proj_wf = qkv_wf + 768 * 256;                            // 256*256 (fragment-major)
  hbf* xn = proj_wf + 256 * 256;                                // B*S*C (fragment-major)
  hbf* qbuf = xn + (size_t)B_ * S_ * C_;                        // B*S*C (q, scaled, [s][c])
  hbf* kg = qbuf + (size_t)B_ * S_ * C_;                        // B*NH*(S/32)*2*[32][16]
  hbf* vg = kg + (size_t)B_ * S_ * C_;                          // B*NH*(S/16)*32*16
  hbf* attn_t = vg + (size_t)B_ * S_ * C_;                      // B*S*C
  float* stats = (float*)(attn_t + (size_t)B_ * S_ * C_);       // 64*8*2 f32 partials

  void* cargs[] = {(void*)&qkv_w, (void*)&proj_w, (void*)&x, (void*)&gn_w, (void*)&gn_b,
                   (void*)&qkv_wf, (void*)&proj_wf, (void*)&stats, (void*)&xn,
                   (void*)&qkv_b, (void*)&qbuf, (void*)&kg, (void*)&vg};
  hipLaunchCooperativeKernel((const void*)fused_pre, dim3(768), dim3(256), cargs, 0, stream);
  attn_kernel<<<dim3(1024), dim3(512), 0, stream>>>(qbuf, kg, vg, attn_t);
  proj_gemm<<<dim3(64, 4, 2), dim3(256), 0, stream>>>(attn_t, proj_wf, proj_b, x, out);
}

// Round 18
// 83.268 us; speedup vs baseline: 3.3148x; 3.3148x over previous
//
#include <hip/hip_runtime.h>
#include <hip/hip_bf16.h>

#define B_ 2
#define C_ 256
#define S_ 4096
#define NH 8
#define HD 32
#define EPSV 1e-5f
// QSCALE * log2(e): scores computed in log2 units so softmax uses exp2
#define QSC2 0.25503487942324256f

typedef __bf16 bf16_t;
typedef bf16_t bf16x8 __attribute__((ext_vector_type(8)));
typedef float f32x4 __attribute__((ext_vector_type(4)));
typedef float f32x16 __attribute__((ext_vector_type(16)));
typedef int i32x2 __attribute__((ext_vector_type(2)));
typedef __hip_bfloat16 hbf;

__device__ inline unsigned cvtpk_bf16(float a, float b) {
  unsigned r;
  asm("v_cvt_pk_bf16_f32 %0, %1, %2" : "=v"(r) : "v"(a), "v"(b));
  return r;
}

// raw hardware exp2 (v_exp_f32): scores are tiny, no range handling needed
#if __has_builtin(__builtin_amdgcn_exp2f)
#define EXP2R(x) __builtin_amdgcn_exp2f(x)
#else
#define EXP2R(x) exp2f(x)
#endif

// ---------------- prep: qkv wfrag + proj wfrag + gn_stats in ONE kernel ----------------
// blocks [0,96): qkv_w -> fragment-major; [96,128): proj_w -> fragment-major;
// [128,640): gn partial sums (deterministic per-chunk partials).
// fragment-major weights: wf[o/32][c/16][o%32][16] from w[o][c], c = 256.
__global__ __launch_bounds__(256) void prep_kernel(const float* __restrict__ qkv_w,
                                                   const float* __restrict__ proj_w,
                                                   const float* __restrict__ x,
                                                   hbf* __restrict__ qkv_wf, hbf* __restrict__ proj_wf,
                                                   float* __restrict__ stats) {
  int blk = blockIdx.x;
  if (blk < 128) {
    const float* src = (blk < 96) ? qkv_w : proj_w;
    hbf* dst = (blk < 96) ? qkv_wf : proj_wf;
    int i = (blk < 96 ? blk : blk - 96) * 256 + threadIdx.x;
    int nchunks = (blk < 96) ? 768 * 32 : 256 * 32;
    if (i < nchunks) {
      int o = i >> 5, c8 = (i & 31) * 8;
      alignas(16) hbf tmp[8];
#pragma unroll
      for (int j = 0; j < 8; j++) tmp[j] = __float2bfloat16(src[(size_t)o * C_ + c8 + j]);
      *(uint4*)&dst[(((size_t)(o >> 5) * 16) + (c8 >> 4)) * 512 + (o & 31) * 16 + (c8 & 15)] = *(uint4*)tmp;
    }
    return;
  }
  // gn_stats: 512 blocks = 64 (b,g) x 8 chunks
  int sb = blk - 128;
  int bg = sb >> 3, chunk = sb & 7;
  const float4* xp4 = (const float4*)(x + (size_t)bg * 8 * S_);
  float sum = 0.f, sumsq = 0.f;
#pragma unroll
  for (int p = 0; p < 4; p++) {
    int i = threadIdx.x + p * 256;            // 1024 float4s: 8 ch x 128
    int ch = i >> 7, s4 = i & 127;
    float4 v = xp4[ch * (S_ >> 2) + chunk * 128 + s4];
    sum += v.x + v.y + v.z + v.w;
    sumsq += v.x * v.x + v.y * v.y + v.z * v.z + v.w * v.w;
  }
#pragma unroll
  for (int off = 32; off > 0; off >>= 1) {
    sum += __shfl_down(sum, off);
    sumsq += __shfl_down(sumsq, off);
  }
  __shared__ float red[2][4];
  int wid = threadIdx.x >> 6;
  if ((threadIdx.x & 63) == 0) { red[0][wid] = sum; red[1][wid] = sumsq; }
  __syncthreads();
  if (threadIdx.x == 0) {
    stats[sb * 2 + 0] = red[0][0] + red[0][1] + red[0][2] + red[0][3];
    stats[sb * 2 + 1] = red[1][0] + red[1][1] + red[1][2] + red[1][3];
  }
}

// ---------------- GroupNorm pass 2: normalize + fragment-major transpose store ----------------
// xn[b][s/32][c/16][s%32][16]; grid 512 = 64 (b,g) x 8 chunks, 256 threads (2 s each)
__global__ __launch_bounds__(256) void gn_apply(const float* __restrict__ x, const float* __restrict__ gw,
                                                const float* __restrict__ gb, const float* __restrict__ stats,
                                                hbf* __restrict__ xn) {
  int bg = blockIdx.x >> 3, chunk = blockIdx.x & 7;
  int b = bg >> 5, g = bg & 31;
  const float* xp = x + (size_t)bg * 8 * S_;
  float sum = 0.f, sumsq = 0.f;
#pragma unroll
  for (int k = 0; k < 8; k++) {               // fixed order: deterministic
    sum += stats[(bg * 8 + k) * 2 + 0];
    sumsq += stats[(bg * 8 + k) * 2 + 1];
  }
  const float inv_n = 1.f / (8 * S_);
  float mean = sum * inv_n;
  float rstd = rsqrtf(fmaxf(sumsq * inv_n - mean * mean, 0.f) + EPSV);
  float scv[8], shv[8];
#pragma unroll
  for (int c = 0; c < 8; c++) {
    scv[c] = gw[g * 8 + c] * rstd;
    shv[c] = gb[g * 8 + c] - mean * scv[c];
  }
#pragma unroll
  for (int p = 0; p < 2; p++) {
    int s = chunk * 512 + p * 256 + threadIdx.x;
    alignas(16) hbf tmp[8];
#pragma unroll
    for (int c = 0; c < 8; c++)
      tmp[c] = __float2bfloat16(xp[(size_t)c * S_ + s] * scv[c] + shv[c]);
    *(uint4*)&xn[(((size_t)b * (S_ >> 5) + (s >> 5)) * 16 + (g >> 1)) * 512 + (s & 31) * 16 + (g & 1) * 8] =
        *(uint4*)tmp;
  }
}

// ---------------- QKV GEMM v2: LDS-free, fragment-major A and B ----------------
__global__ __launch_bounds__(512, 4) void qkv_gemm(const hbf* __restrict__ xn, const hbf* __restrict__ wf,
                                                   const float* __restrict__ bias,
                                                   hbf* __restrict__ qbuf, hbf* __restrict__ kg,
                                                   hbf* __restrict__ vg) {
  int bt = blockIdx.z;
  int m0 = blockIdx.x * 128;          // s-base within batch
  int n0 = blockIdx.y * 128;          // o-base
  int tid = threadIdx.x, lane = tid & 63, w = tid >> 6;
  int wq = w & 3, wo = w >> 2;
  int l31 = lane & 31, hi = lane >> 5;
  const int loff = l31 * 16 + hi * 8;
  const hbf* ap = xn + ((size_t)bt * (S_ >> 5) + (m0 >> 5) + wq) * 8192;
  int oc0 = n0 + wo * 64;
  const hbf* bp0 = wf + (size_t)(oc0 >> 5) * 8192;
  const hbf* bp1 = bp0 + 8192;
  f32x16 acc0 = {0.f,0.f,0.f,0.f,0.f,0.f,0.f,0.f,0.f,0.f,0.f,0.f,0.f,0.f,0.f,0.f};
  f32x16 acc1 = acc0;
#pragma unroll 4
  for (int ks = 0; ks < 16; ++ks) {
    bf16x8 af = *(const bf16x8*)(ap + ks * 512 + loff);
    bf16x8 b0 = *(const bf16x8*)(bp0 + ks * 512 + loff);
    bf16x8 b1 = *(const bf16x8*)(bp1 + ks * 512 + loff);
    acc0 = __builtin_amdgcn_mfma_f32_32x32x16_bf16(af, b0, acc0, 0, 0, 0);
    acc1 = __builtin_amdgcn_mfma_f32_32x32x16_bf16(af, b1, acc1, 0, 0, 0);
  }
  int s_base = m0 + wq * 32;
#pragma unroll
  for (int ct = 0; ct < 2; ++ct) {
    f32x16 a = ct ? acc1 : acc0;
    int oc = oc0 + ct * 32;           // uniform per col-tile
    int o = oc + l31;
    float bs = bias[o];
    if (oc < 256) {
#pragma unroll
      for (int r = 0; r < 16; r++) {
        int s = s_base + (r & 3) + 8 * (r >> 2) + 4 * hi;
        qbuf[((size_t)bt * S_ + s) * C_ + o] = __float2bfloat16((a[r] + bs) * QSC2);
      }
    } else if (oc < 512) {
      int hh = (oc - 256) >> 5;
      const size_t khead = (size_t)(bt * NH + hh) * (S_ >> 5);
#pragma unroll
      for (int r = 0; r < 16; r++) {
        int s = s_base + (r & 3) + 8 * (r >> 2) + 4 * hi;
        kg[(khead + (s >> 5)) * 1024 + (l31 >> 4) * 512 + (s & 31) * 16 + (l31 & 15)] =
            __float2bfloat16(a[r] + bs);
      }
    } else {
      int hh = (oc - 512) >> 5;
      const size_t vhead = (size_t)(bt * NH + hh) * (S_ >> 4);
#pragma unroll
      for (int r = 0; r < 16; r++) {
        int s = s_base + (r & 3) + 8 * (r >> 2) + 4 * hi;
        vg[(vhead + (s >> 4)) * 512 + l31 * 16 + (s & 15)] = __float2bfloat16(a[r] + bs);
      }
    }
  }
}

// softmax numerator + P relayout + PV + l (ones-MFMA) for ONE 32-t tile
__device__ inline void softmax_pv(f32x16 sc, bf16x8 va0, bf16x8 va1, bf16x8 ones,
                                  f32x16& o_acc, f32x16& l_acc) {
#pragma unroll
  for (int i = 0; i < 16; i++) sc[i] = EXP2R(sc[i]);
#pragma unroll
  for (int kb = 0; kb < 2; kb++) {
    unsigned a0 = cvtpk_bf16(sc[kb * 8 + 0], sc[kb * 8 + 1]);
    unsigned b0 = cvtpk_bf16(sc[kb * 8 + 2], sc[kb * 8 + 3]);
    unsigned a1 = cvtpk_bf16(sc[kb * 8 + 4], sc[kb * 8 + 5]);
    unsigned b1 = cvtpk_bf16(sc[kb * 8 + 6], sc[kb * 8 + 7]);
    i32x2 ra = __builtin_amdgcn_permlane32_swap((int)a0, (int)a1, false, false);
    i32x2 rb = __builtin_amdgcn_permlane32_swap((int)b0, (int)b1, false, false);
    union { unsigned u[4]; bf16x8 v; } pf;
    pf.u[0] = (unsigned)ra[0]; pf.u[1] = (unsigned)rb[0];
    pf.u[2] = (unsigned)ra[1]; pf.u[3] = (unsigned)rb[1];
    // l on the MFMA pipe: D[i][q] += sum_k P[k][q] (rows identical)
    l_acc = __builtin_amdgcn_mfma_f32_32x32x16_bf16(ones, pf.v, l_acc, 0, 0, 0);
    o_acc = __builtin_amdgcn_mfma_f32_32x32x16_bf16(kb ? va1 : va0, pf.v, o_acc, 0, 0, 0);
  }
}

// ---------------- Flash attention v15: ping-pong pipeline + l via ones-MFMA ----------------
// Block: 512 threads, 8 waves = 2 q-subtiles(32 rows) x 4 t-quarters(1024 t each); 1024 blocks.
// LDS-free main loop; K/V fragment-major. Pipeline: QK[tile it] MFMAs issue before the
// exp2/cvt/perm VALU block of tile it-1. l accumulated by mfma(ones, P) on the MFMA pipe.
__global__ __launch_bounds__(512, 4) void attn_kernel(const hbf* __restrict__ qbuf, const hbf* __restrict__ kg,
                                                      const hbf* __restrict__ vg, hbf* __restrict__ attn_t) {
  int bid = blockIdx.x;
  int xcd = bid & 7, idx = bid >> 3;       // 128 blocks per XCD
  int combo = (xcd << 1) | (idx >> 6);     // 16 (bt,h) combos; 2 per XCD
  int bt = combo >> 3, h = combo & 7;
  int s0 = (idx & 63) << 6;                // 64 q-blocks of 64
  int tid = threadIdx.x, lane = tid & 63, w = tid >> 6;
  int wq = w & 1, wt = w >> 1;
  int l31 = lane & 31, hi = lane >> 5;
  const int loff = (l31 << 4) + (hi << 3);
  int qrow = s0 + wq * 32 + l31;
  bf16x8 qf0 = *(const bf16x8*)&qbuf[((size_t)bt * S_ + qrow) * C_ + h * HD + hi * 8];
  bf16x8 qf1 = *(const bf16x8*)&qbuf[((size_t)bt * S_ + qrow) * C_ + h * HD + 16 + hi * 8];
  bf16x8 ones;
#pragma unroll
  for (int i = 0; i < 8; i++) ones[i] = (bf16_t)1.0f;
  f32x16 o_acc = {0.f,0.f,0.f,0.f,0.f,0.f,0.f,0.f,0.f,0.f,0.f,0.f,0.f,0.f,0.f,0.f};
  f32x16 l_acc = o_acc;
  const f32x16 z16 = o_acc;
  const int tq0 = wt << 10;
  const hbf* kq = kg + ((size_t)(bt * NH + h) * (S_ >> 5) + (tq0 >> 5)) * 1024;
  const hbf* vq = vg + ((size_t)(bt * NH + h) * (S_ >> 4) + (tq0 >> 4)) * 512;
  // ---- prologue: scores(0); carry kaB = K[1], vaA = V[0] ----
  bf16x8 kaB0 = *(const bf16x8*)(kq + loff);
  bf16x8 kaB1 = *(const bf16x8*)(kq + loff + 512);
  f32x16 scA = __builtin_amdgcn_mfma_f32_32x32x16_bf16(kaB0, qf0, z16, 0, 0, 0);
  scA = __builtin_amdgcn_mfma_f32_32x32x16_bf16(kaB1, qf1, scA, 0, 0, 0);   // scores(0)
  kaB0 = *(const bf16x8*)(kq + loff + 1024);                                 // K[1]
  kaB1 = *(const bf16x8*)(kq + loff + 1536);
  bf16x8 vaA0 = *(const bf16x8*)(vq + loff);                                 // V[0]
  bf16x8 vaA1 = *(const bf16x8*)(vq + loff + 512);
  kq += 2048;   // -> K[2] base
  vq += 1024;   // -> V[1] base
  // ---- steady state: j = 0..14, tiles (2j, 2j+1) ----
  for (int j = 0; j < 15; ++j) {
    bf16x8 vaB0 = *(const bf16x8*)(vq + loff);            // V[2j+1]
    bf16x8 vaB1 = *(const bf16x8*)(vq + loff + 512);
    bf16x8 knA0 = *(const bf16x8*)(kq + loff);            // K[2j+2]
    bf16x8 knA1 = *(const bf16x8*)(kq + loff + 512);
    f32x16 scB = __builtin_amdgcn_mfma_f32_32x32x16_bf16(kaB0, qf0, z16, 0, 0, 0);
    scB = __builtin_amdgcn_mfma_f32_32x32x16_bf16(kaB1, qf1, scB, 0, 0, 0);  // scores(2j+1)
    kaB0 = *(const bf16x8*)(kq + loff + 1024);            // K[2j+3] (reload in place)
    kaB1 = *(const bf16x8*)(kq + loff + 1536);
    softmax_pv(scA, vaA0, vaA1, ones, o_acc, l_acc);      // tile 2j
    vaA0 = *(const bf16x8*)(vq + loff + 1024);            // V[2j+2] (reload in place)
    vaA1 = *(const bf16x8*)(vq + loff + 1536);
    scA = __builtin_amdgcn_mfma_f32_32x32x16_bf16(knA0, qf0, z16, 0, 0, 0);
    scA = __builtin_amdgcn_mfma_f32_32x32x16_bf16(knA1, qf1, scA, 0, 0, 0);  // scores(2j+2)
    softmax_pv(scB, vaB0, vaB1, ones, o_acc, l_acc);      // tile 2j+1
    kq += 2048; vq += 2048;
  }
  // ---- epilogue: tiles 30, 31 ----
  {
    bf16x8 vaB0 = *(const bf16x8*)(vq + loff);
    bf16x8 vaB1 = *(const bf16x8*)(vq + loff + 512);
    f32x16 scB = __builtin_amdgcn_mfma_f32_32x32x16_bf16(kaB0, qf0, z16, 0, 0, 0);
    scB = __builtin_amdgcn_mfma_f32_32x32x16_bf16(kaB1, qf1, scB, 0, 0, 0);  // scores(31)
    softmax_pv(scA, vaA0, vaA1, ones, o_acc, l_acc);      // tile 30
    softmax_pv(scB, vaB0, vaB1, ones, o_acc, l_acc);      // tile 31
  }
  // combine the 4 t-quarter partials (pure sums under fixed-max softmax)
  __shared__ f32x16 ored[6 * 64];
  __shared__ float lred[8 * 64];
  __syncthreads();
  lred[(w << 6) + lane] = l_acc[0];   // full column sum for this quarter (rows & hi-halves identical)
  if (wt > 0) ored[((w - 2) << 6) + lane] = o_acc;
  __syncthreads();
  if (wt == 0) {
    float l_tot = 0.f;
#pragma unroll
    for (int k = 0; k < 4; k++)
      l_tot += lred[((wq + 2 * k) << 6) + l31];   // one term per t-quarter
    f32x16 o = o_acc;
#pragma unroll
    for (int k = 0; k < 3; k++) {
      f32x16 t2 = ored[((wq + 2 * k) << 6) + lane];
#pragma unroll
      for (int i = 0; i < 16; i++) o[i] += t2[i];
    }
    float inv_l = 1.0f / l_tot;
#pragma unroll
    for (int c2 = 0; c2 < 4; c2++) {
      alignas(8) hbf tmp[4];
#pragma unroll
      for (int r = 0; r < 4; r++) tmp[r] = __float2bfloat16(o[c2 * 4 + r] * inv_l);
      *(uint2*)&attn_t[((size_t)bt * S_ + qrow) * C_ + h * HD + c2 * 8 + hi * 4] = *(uint2*)tmp;
    }
  }
}

// ---------------- Proj GEMM v2: LDS-free, fragment-major W, coalesced f32 out ----------------
__global__ __launch_bounds__(256) void proj_gemm(const hbf* __restrict__ attn_t, const hbf* __restrict__ wf,
                                                 const float* __restrict__ bias, const float* __restrict__ x,
                                                 float* __restrict__ out) {
  int bt = blockIdx.z;
  int s_blk = blockIdx.x * 64;
  int o_blk = blockIdx.y * 64;
  int tid = threadIdx.x, lane = tid & 63, w = tid >> 6;
  int wo = w & 1, ws = w >> 1;
  int l31 = lane & 31, hi = lane >> 5;
  const int loff = l31 * 16 + hi * 8;
  int o0 = o_blk + wo * 32;
  int s0 = s_blk + ws * 32;
  const hbf* ap = wf + (size_t)(o0 >> 5) * 8192;               // fragment-major W chunk
  const hbf* bp = attn_t + ((size_t)bt * S_ + s0 + l31) * C_ + hi * 8;  // row s = s0+l31
  f32x16 acc = {0.f,0.f,0.f,0.f,0.f,0.f,0.f,0.f,0.f,0.f,0.f,0.f,0.f,0.f,0.f,0.f};
#pragma unroll 4
  for (int ks = 0; ks < 16; ++ks) {
    bf16x8 af = *(const bf16x8*)(ap + ks * 512 + loff);
    bf16x8 bf_ = *(const bf16x8*)(bp + ks * 16);
    acc = __builtin_amdgcn_mfma_f32_32x32x16_bf16(af, bf_, acc, 0, 0, 0);
  }
  int s = s0 + l31;
#pragma unroll
  for (int r = 0; r < 16; r++) {
    int o = o0 + (r & 3) + 8 * (r >> 2) + 4 * hi;
    size_t idx = ((size_t)bt * C_ + o) * S_ + s;
    out[idx] = acc[r] + bias[o] + x[idx];
  }
}

extern "C" void kernel_launch(void* const* d_in, const int* in_sizes, int n_in,
                              void* d_out, int out_size, void* d_ws, size_t ws_size,
                              hipStream_t stream) {
  const float* x = (const float*)d_in[0];
  const float* gn_w = (const float*)d_in[1];
  const float* gn_b = (const float*)d_in[2];
  const float* qkv_w = (const float*)d_in[3];
  const float* qkv_b = (const float*)d_in[4];
  const float* proj_w = (const float*)d_in[5];
  const float* proj_b = (const float*)d_in[6];
  float* out = (float*)d_out;

  hbf* qkv_wf = (hbf*)d_ws;                                     // 768*256 (fragment-major)
  hbf* proj_wf = qkv_wf + 768 * 256;                            // 256*256 (fragment-major)
  hbf* xn = proj_wf + 256 * 256;                                // B*S*C (fragment-major)
  hbf* qbuf = xn + (size_t)B_ * S_ * C_;                        // B*S*C (q, scaled, [s][c])
  hbf* kg = qbuf + (size_t)B_ * S_ * C_;                        // B*NH*(S/32)*2*[32][16]
  hbf* vg = kg + (size_t)B_ * S_ * C_;                          // B*NH*(S/16)*32*16
  hbf* attn_t = vg + (size_t)B_ * S_ * C_;                      // B*S*C
  float* stats = (float*)(attn_t + (size_t)B_ * S_ * C_);       // 64*8*2 f32 partials

  dim3 blk(256);
  prep_kernel<<<640, blk, 0, stream>>>(qkv_w, proj_w, x, qkv_wf, proj_wf, stats);
  gn_apply<<<512, blk, 0, stream>>>(x, gn_w, gn_b, stats, xn);
  qkv_gemm<<<dim3(32, 6, 2), dim3(512), 0, stream>>>(xn, qkv_wf, qkv_b, qbuf, kg, vg);
  attn_kernel<<<dim3(1024), dim3(512), 0, stream>>>(qbuf, kg, vg, attn_t);
  proj_gemm<<<dim3(64, 4, 2), blk, 0, stream>>>(attn_t, proj_wf, proj_b, x, out);
}

// Round 19
// 79.113 us; speedup vs baseline: 3.4888x; 1.0525x over previous
//
#include <hip/hip_runtime.h>
#include <hip/hip_bf16.h>

#define B_ 2
#define C_ 256
#define S_ 4096
#define NH 8
#define HD 32
#define EPSV 1e-5f
// QSCALE * log2(e): scores computed in log2 units so softmax uses exp2
#define QSC2 0.25503487942324256f

typedef __bf16 bf16_t;
typedef bf16_t bf16x8 __attribute__((ext_vector_type(8)));
typedef float f32x4 __attribute__((ext_vector_type(4)));
typedef float f32x16 __attribute__((ext_vector_type(16)));
typedef int i32x2 __attribute__((ext_vector_type(2)));
typedef __hip_bfloat16 hbf;

__device__ inline unsigned cvtpk_bf16(float a, float b) {
  unsigned r;
  asm("v_cvt_pk_bf16_f32 %0, %1, %2" : "=v"(r) : "v"(a), "v"(b));
  return r;
}

// raw hardware exp2 (v_exp_f32): scores are tiny, no range handling needed
#if __has_builtin(__builtin_amdgcn_exp2f)
#define EXP2R(x) __builtin_amdgcn_exp2f(x)
#else
#define EXP2R(x) exp2f(x)
#endif

// ---------------- prep: qkv wfrag + proj wfrag + gn_stats in ONE kernel ----------------
// blocks [0,96): qkv_w -> fragment-major; [96,128): proj_w -> fragment-major;
// [128,640): gn partial sums (deterministic per-chunk partials).
// fragment-major weights: wf[o/32][c/16][o%32][16] from w[o][c], c = 256.
__global__ __launch_bounds__(256) void prep_kernel(const float* __restrict__ qkv_w,
                                                   const float* __restrict__ proj_w,
                                                   const float* __restrict__ x,
                                                   hbf* __restrict__ qkv_wf, hbf* __restrict__ proj_wf,
                                                   float* __restrict__ stats) {
  int blk = blockIdx.x;
  if (blk < 128) {
    const float* src = (blk < 96) ? qkv_w : proj_w;
    hbf* dst = (blk < 96) ? qkv_wf : proj_wf;
    int i = (blk < 96 ? blk : blk - 96) * 256 + threadIdx.x;
    int nchunks = (blk < 96) ? 768 * 32 : 256 * 32;
    if (i < nchunks) {
      int o = i >> 5, c8 = (i & 31) * 8;
      alignas(16) hbf tmp[8];
#pragma unroll
      for (int j = 0; j < 8; j++) tmp[j] = __float2bfloat16(src[(size_t)o * C_ + c8 + j]);
      *(uint4*)&dst[(((size_t)(o >> 5) * 16) + (c8 >> 4)) * 512 + (o & 31) * 16 + (c8 & 15)] = *(uint4*)tmp;
    }
    return;
  }
  // gn_stats: 512 blocks = 64 (b,g) x 8 chunks
  int sb = blk - 128;
  int bg = sb >> 3, chunk = sb & 7;
  const float4* xp4 = (const float4*)(x + (size_t)bg * 8 * S_);
  float sum = 0.f, sumsq = 0.f;
#pragma unroll
  for (int p = 0; p < 4; p++) {
    int i = threadIdx.x + p * 256;            // 1024 float4s: 8 ch x 128
    int ch = i >> 7, s4 = i & 127;
    float4 v = xp4[ch * (S_ >> 2) + chunk * 128 + s4];
    sum += v.x + v.y + v.z + v.w;
    sumsq += v.x * v.x + v.y * v.y + v.z * v.z + v.w * v.w;
  }
#pragma unroll
  for (int off = 32; off > 0; off >>= 1) {
    sum += __shfl_down(sum, off);
    sumsq += __shfl_down(sumsq, off);
  }
  __shared__ float red[2][4];
  int wid = threadIdx.x >> 6;
  if ((threadIdx.x & 63) == 0) { red[0][wid] = sum; red[1][wid] = sumsq; }
  __syncthreads();
  if (threadIdx.x == 0) {
    stats[sb * 2 + 0] = red[0][0] + red[0][1] + red[0][2] + red[0][3];
    stats[sb * 2 + 1] = red[1][0] + red[1][1] + red[1][2] + red[1][3];
  }
}

// ---------------- GroupNorm pass 2: normalize + fragment-major transpose store ----------------
// xn[b][s/32][c/16][s%32][16]; grid 512 = 64 (b,g) x 8 chunks, 256 threads (2 s each)
__global__ __launch_bounds__(256) void gn_apply(const float* __restrict__ x, const float* __restrict__ gw,
                                                const float* __restrict__ gb, const float* __restrict__ stats,
                                                hbf* __restrict__ xn) {
  int bg = blockIdx.x >> 3, chunk = blockIdx.x & 7;
  int b = bg >> 5, g = bg & 31;
  const float* xp = x + (size_t)bg * 8 * S_;
  float sum = 0.f, sumsq = 0.f;
#pragma unroll
  for (int k = 0; k < 8; k++) {               // fixed order: deterministic
    sum += stats[(bg * 8 + k) * 2 + 0];
    sumsq += stats[(bg * 8 + k) * 2 + 1];
  }
  const float inv_n = 1.f / (8 * S_);
  float mean = sum * inv_n;
  float rstd = rsqrtf(fmaxf(sumsq * inv_n - mean * mean, 0.f) + EPSV);
  float scv[8], shv[8];
#pragma unroll
  for (int c = 0; c < 8; c++) {
    scv[c] = gw[g * 8 + c] * rstd;
    shv[c] = gb[g * 8 + c] - mean * scv[c];
  }
#pragma unroll
  for (int p = 0; p < 2; p++) {
    int s = chunk * 512 + p * 256 + threadIdx.x;
    alignas(16) hbf tmp[8];
#pragma unroll
    for (int c = 0; c < 8; c++)
      tmp[c] = __float2bfloat16(xp[(size_t)c * S_ + s] * scv[c] + shv[c]);
    *(uint4*)&xn[(((size_t)b * (S_ >> 5) + (s >> 5)) * 16 + (g >> 1)) * 512 + (s & 31) * 16 + (g & 1) * 8] =
        *(uint4*)tmp;
  }
}

// ---------------- QKV GEMM v2: LDS-free, fragment-major A and B ----------------
__global__ __launch_bounds__(512, 4) void qkv_gemm(const hbf* __restrict__ xn, const hbf* __restrict__ wf,
                                                   const float* __restrict__ bias,
                                                   hbf* __restrict__ qbuf, hbf* __restrict__ kg,
                                                   hbf* __restrict__ vg) {
  int bt = blockIdx.z;
  int m0 = blockIdx.x * 128;          // s-base within batch
  int n0 = blockIdx.y * 128;          // o-base
  int tid = threadIdx.x, lane = tid & 63, w = tid >> 6;
  int wq = w & 3, wo = w >> 2;
  int l31 = lane & 31, hi = lane >> 5;
  const int loff = l31 * 16 + hi * 8;
  const hbf* ap = xn + ((size_t)bt * (S_ >> 5) + (m0 >> 5) + wq) * 8192;
  int oc0 = n0 + wo * 64;
  const hbf* bp0 = wf + (size_t)(oc0 >> 5) * 8192;
  const hbf* bp1 = bp0 + 8192;
  f32x16 acc0 = {0.f,0.f,0.f,0.f,0.f,0.f,0.f,0.f,0.f,0.f,0.f,0.f,0.f,0.f,0.f,0.f};
  f32x16 acc1 = acc0;
#pragma unroll 4
  for (int ks = 0; ks < 16; ++ks) {
    bf16x8 af = *(const bf16x8*)(ap + ks * 512 + loff);
    bf16x8 b0 = *(const bf16x8*)(bp0 + ks * 512 + loff);
    bf16x8 b1 = *(const bf16x8*)(bp1 + ks * 512 + loff);
    acc0 = __builtin_amdgcn_mfma_f32_32x32x16_bf16(af, b0, acc0, 0, 0, 0);
    acc1 = __builtin_amdgcn_mfma_f32_32x32x16_bf16(af, b1, acc1, 0, 0, 0);
  }
  int s_base = m0 + wq * 32;
#pragma unroll
  for (int ct = 0; ct < 2; ++ct) {
    f32x16 a = ct ? acc1 : acc0;
    int oc = oc0 + ct * 32;           // uniform per col-tile
    int o = oc + l31;
    float bs = bias[o];
    if (oc < 256) {
#pragma unroll
      for (int r = 0; r < 16; r++) {
        int s = s_base + (r & 3) + 8 * (r >> 2) + 4 * hi;
        qbuf[((size_t)bt * S_ + s) * C_ + o] = __float2bfloat16((a[r] + bs) * QSC2);
      }
    } else if (oc < 512) {
      int hh = (oc - 256) >> 5;
      const size_t khead = (size_t)(bt * NH + hh) * (S_ >> 5);
#pragma unroll
      for (int r = 0; r < 16; r++) {
        int s = s_base + (r & 3) + 8 * (r >> 2) + 4 * hi;
        kg[(khead + (s >> 5)) * 1024 + (l31 >> 4) * 512 + (s & 31) * 16 + (l31 & 15)] =
            __float2bfloat16(a[r] + bs);
      }
    } else {
      int hh = (oc - 512) >> 5;
      const size_t vhead = (size_t)(bt * NH + hh) * (S_ >> 4);
#pragma unroll
      for (int r = 0; r < 16; r++) {
        int s = s_base + (r & 3) + 8 * (r >> 2) + 4 * hi;
        vg[(vhead + (s >> 4)) * 512 + l31 * 16 + (s & 15)] = __float2bfloat16(a[r] + bs);
      }
    }
  }
}

// softmax numerator + P relayout + PV for ONE 32-t tile (consumes sc of that tile)
// l via VALU tree (measured best split: r18 showed ones-MFMA overloads the MFMA pipe)
__device__ inline void softmax_pv(f32x16 sc, bf16x8 va0, bf16x8 va1,
                                  f32x16& o_acc, float& l_run) {
#pragma unroll
  for (int i = 0; i < 16; i++) sc[i] = EXP2R(sc[i]);
  {
    float s0a = sc[0] + sc[1], s1a = sc[2] + sc[3], s2a = sc[4] + sc[5], s3a = sc[6] + sc[7];
    float s4a = sc[8] + sc[9], s5a = sc[10] + sc[11], s6a = sc[12] + sc[13], s7a = sc[14] + sc[15];
    s0a += s1a; s2a += s3a; s4a += s5a; s6a += s7a;
    s0a += s2a; s4a += s6a;
    l_run += s0a + s4a;
  }
#pragma unroll
  for (int kb = 0; kb < 2; kb++) {
    unsigned a0 = cvtpk_bf16(sc[kb * 8 + 0], sc[kb * 8 + 1]);
    unsigned b0 = cvtpk_bf16(sc[kb * 8 + 2], sc[kb * 8 + 3]);
    unsigned a1 = cvtpk_bf16(sc[kb * 8 + 4], sc[kb * 8 + 5]);
    unsigned b1 = cvtpk_bf16(sc[kb * 8 + 6], sc[kb * 8 + 7]);
    i32x2 ra = __builtin_amdgcn_permlane32_swap((int)a0, (int)a1, false, false);
    i32x2 rb = __builtin_amdgcn_permlane32_swap((int)b0, (int)b1, false, false);
    union { unsigned u[4]; bf16x8 v; } pf;
    pf.u[0] = (unsigned)ra[0]; pf.u[1] = (unsigned)rb[0];
    pf.u[2] = (unsigned)ra[1]; pf.u[3] = (unsigned)rb[1];
    __builtin_amdgcn_s_setprio(1);
    o_acc = __builtin_amdgcn_mfma_f32_32x32x16_bf16(kb ? va1 : va0, pf.v, o_acc, 0, 0, 0);
    __builtin_amdgcn_s_setprio(0);
  }
}

// ---------------- Flash attention v16: v14 ping-pong pipeline + s_setprio on MFMA bursts ----------------
// Block: 512 threads, 8 waves = 2 q-subtiles(32 rows) x 4 t-quarters(1024 t each); 1024 blocks.
// LDS-free main loop; K/V fragment-major. Pipeline: QK[tile it] MFMAs issue before the
// exp2/cvt/perm VALU block of tile it-1. l via VALU tree (r18 A/B winner). setprio(1) wraps
// MFMA bursts so waves in their MFMA phase win issue arbitration over co-resident VALU waves (T5).
__global__ __launch_bounds__(512, 4) void attn_kernel(const hbf* __restrict__ qbuf, const hbf* __restrict__ kg,
                                                      const hbf* __restrict__ vg, hbf* __restrict__ attn_t) {
  int bid = blockIdx.x;
  int xcd = bid & 7, idx = bid >> 3;       // 128 blocks per XCD
  int combo = (xcd << 1) | (idx >> 6);     // 16 (bt,h) combos; 2 per XCD
  int bt = combo >> 3, h = combo & 7;
  int s0 = (idx & 63) << 6;                // 64 q-blocks of 64
  int tid = threadIdx.x, lane = tid & 63, w = tid >> 6;
  int wq = w & 1, wt = w >> 1;
  int l31 = lane & 31, hi = lane >> 5;
  const int loff = (l31 << 4) + (hi << 3);
  int qrow = s0 + wq * 32 + l31;
  bf16x8 qf0 = *(const bf16x8*)&qbuf[((size_t)bt * S_ + qrow) * C_ + h * HD + hi * 8];
  bf16x8 qf1 = *(const bf16x8*)&qbuf[((size_t)bt * S_ + qrow) * C_ + h * HD + 16 + hi * 8];
  f32x16 o_acc = {0.f,0.f,0.f,0.f,0.f,0.f,0.f,0.f,0.f,0.f,0.f,0.f,0.f,0.f,0.f,0.f};
  const f32x16 z16 = o_acc;
  float l_run = 0.f;
  const int tq0 = wt << 10;
  const hbf* kq = kg + ((size_t)(bt * NH + h) * (S_ >> 5) + (tq0 >> 5)) * 1024;
  const hbf* vq = vg + ((size_t)(bt * NH + h) * (S_ >> 4) + (tq0 >> 4)) * 512;
  // ---- prologue: scores(0); carry kaB = K[1], vaA = V[0] ----
  bf16x8 kaB0 = *(const bf16x8*)(kq + loff);
  bf16x8 kaB1 = *(const bf16x8*)(kq + loff + 512);
  f32x16 scA = __builtin_amdgcn_mfma_f32_32x32x16_bf16(kaB0, qf0, z16, 0, 0, 0);
  scA = __builtin_amdgcn_mfma_f32_32x32x16_bf16(kaB1, qf1, scA, 0, 0, 0);   // scores(0)
  kaB0 = *(const bf16x8*)(kq + loff + 1024);                                 // K[1]
  kaB1 = *(const bf16x8*)(kq + loff + 1536);
  bf16x8 vaA0 = *(const bf16x8*)(vq + loff);                                 // V[0]
  bf16x8 vaA1 = *(const bf16x8*)(vq + loff + 512);
  kq += 2048;   // -> K[2] base
  vq += 1024;   // -> V[1] base
  // ---- steady state: j = 0..14, tiles (2j, 2j+1) ----
  for (int j = 0; j < 15; ++j) {
    bf16x8 vaB0 = *(const bf16x8*)(vq + loff);            // V[2j+1]
    bf16x8 vaB1 = *(const bf16x8*)(vq + loff + 512);
    bf16x8 knA0 = *(const bf16x8*)(kq + loff);            // K[2j+2]
    bf16x8 knA1 = *(const bf16x8*)(kq + loff + 512);
    __builtin_amdgcn_s_setprio(1);
    f32x16 scB = __builtin_amdgcn_mfma_f32_32x32x16_bf16(kaB0, qf0, z16, 0, 0, 0);
    scB = __builtin_amdgcn_mfma_f32_32x32x16_bf16(kaB1, qf1, scB, 0, 0, 0);  // scores(2j+1)
    __builtin_amdgcn_s_setprio(0);
    kaB0 = *(const bf16x8*)(kq + loff + 1024);            // K[2j+3] (reload in place)
    kaB1 = *(const bf16x8*)(kq + loff + 1536);
    softmax_pv(scA, vaA0, vaA1, o_acc, l_run);            // tile 2j
    vaA0 = *(const bf16x8*)(vq + loff + 1024);            // V[2j+2] (reload in place)
    vaA1 = *(const bf16x8*)(vq + loff + 1536);
    __builtin_amdgcn_s_setprio(1);
    scA = __builtin_amdgcn_mfma_f32_32x32x16_bf16(knA0, qf0, z16, 0, 0, 0);
    scA = __builtin_amdgcn_mfma_f32_32x32x16_bf16(knA1, qf1, scA, 0, 0, 0);  // scores(2j+2)
    __builtin_amdgcn_s_setprio(0);
    softmax_pv(scB, vaB0, vaB1, o_acc, l_run);            // tile 2j+1
    kq += 2048; vq += 2048;
  }
  // ---- epilogue: tiles 30, 31 ----
  {
    bf16x8 vaB0 = *(const bf16x8*)(vq + loff);
    bf16x8 vaB1 = *(const bf16x8*)(vq + loff + 512);
    f32x16 scB = __builtin_amdgcn_mfma_f32_32x32x16_bf16(kaB0, qf0, z16, 0, 0, 0);
    scB = __builtin_amdgcn_mfma_f32_32x32x16_bf16(kaB1, qf1, scB, 0, 0, 0);  // scores(31)
    softmax_pv(scA, vaA0, vaA1, o_acc, l_run);            // tile 30
    softmax_pv(scB, vaB0, vaB1, o_acc, l_run);            // tile 31
  }
  // combine the 4 t-quarter partials (pure sums under fixed-max softmax)
  __shared__ f32x16 ored[6 * 64];
  __shared__ float lred[8 * 64];
  __syncthreads();
  lred[(w << 6) + lane] = l_run;
  if (wt > 0) ored[((w - 2) << 6) + lane] = o_acc;
  __syncthreads();
  if (wt == 0) {
    float l_tot = 0.f;
#pragma unroll
    for (int k = 0; k < 4; k++) {
      int wp = wq + 2 * k;
      l_tot += lred[(wp << 6) + l31] + lred[(wp << 6) + 32 + l31];
    }
    f32x16 o = o_acc;
#pragma unroll
    for (int k = 0; k < 3; k++) {
      f32x16 t2 = ored[((wq + 2 * k) << 6) + lane];
#pragma unroll
      for (int i = 0; i < 16; i++) o[i] += t2[i];
    }
    float inv_l = 1.0f / l_tot;
#pragma unroll
    for (int c2 = 0; c2 < 4; c2++) {
      alignas(8) hbf tmp[4];
#pragma unroll
      for (int r = 0; r < 4; r++) tmp[r] = __float2bfloat16(o[c2 * 4 + r] * inv_l);
      *(uint2*)&attn_t[((size_t)bt * S_ + qrow) * C_ + h * HD + c2 * 8 + hi * 4] = *(uint2*)tmp;
    }
  }
}

// ---------------- Proj GEMM v2: LDS-free, fragment-major W, coalesced f32 out ----------------
__global__ __launch_bounds__(256) void proj_gemm(const hbf* __restrict__ attn_t, const hbf* __restrict__ wf,
                                                 const float* __restrict__ bias, const float* __restrict__ x,
                                                 float* __restrict__ out) {
  int bt = blockIdx.z;
  int s_blk = blockIdx.x * 64;
  int o_blk = blockIdx.y * 64;
  int tid = threadIdx.x, lane = tid & 63, w = tid >> 6;
  int wo = w & 1, ws = w >> 1;
  int l31 = lane & 31, hi = lane >> 5;
  const int loff = l31 * 16 + hi * 8;
  int o0 = o_blk + wo * 32;
  int s0 = s_blk + ws * 32;
  const hbf* ap = wf + (size_t)(o0 >> 5) * 8192;               // fragment-major W chunk
  const hbf* bp = attn_t + ((size_t)bt * S_ + s0 + l31) * C_ + hi * 8;  // row s = s0+l31
  f32x16 acc = {0.f,0.f,0.f,0.f,0.f,0.f,0.f,0.f,0.f,0.f,0.f,0.f,0.f,0.f,0.f,0.f};
#pragma unroll 4
  for (int ks = 0; ks < 16; ++ks) {
    bf16x8 af = *(const bf16x8*)(ap + ks * 512 + loff);
    bf16x8 bf_ = *(const bf16x8*)(bp + ks * 16);
    acc = __builtin_amdgcn_mfma_f32_32x32x16_bf16(af, bf_, acc, 0, 0, 0);
  }
  int s = s0 + l31;
#pragma unroll
  for (int r = 0; r < 16; r++) {
    int o = o0 + (r & 3) + 8 * (r >> 2) + 4 * hi;
    size_t idx = ((size_t)bt * C_ + o) * S_ + s;
    out[idx] = acc[r] + bias[o] + x[idx];
  }
}

extern "C" void kernel_launch(void* const* d_in, const int* in_sizes, int n_in,
                              void* d_out, int out_size, void* d_ws, size_t ws_size,
                              hipStream_t stream) {
  const float* x = (const float*)d_in[0];
  const float* gn_w = (const float*)d_in[1];
  const float* gn_b = (const float*)d_in[2];
  const float* qkv_w = (const float*)d_in[3];
  const float* qkv_b = (const float*)d_in[4];
  const float* proj_w = (const float*)d_in[5];
  const float* proj_b = (const float*)d_in[6];
  float* out = (float*)d_out;

  hbf* qkv_wf = (hbf*)d_ws;                                     // 768*256 (fragment-major)
  hbf* proj_wf = qkv_wf + 768 * 256;                            // 256*256 (fragment-major)
  hbf* xn = proj_wf + 256 * 256;                                // B*S*C (fragment-major)
  hbf* qbuf = xn + (size_t)B_ * S_ * C_;                        // B*S*C (q, scaled, [s][c])
  hbf* kg = qbuf + (size_t)B_ * S_ * C_;                        // B*NH*(S/32)*2*[32][16]
  hbf* vg = kg + (size_t)B_ * S_ * C_;                          // B*NH*(S/16)*32*16
  hbf* attn_t = vg + (size_t)B_ * S_ * C_;                      // B*S*C
  float* stats = (float*)(attn_t + (size_t)B_ * S_ * C_);       // 64*8*2 f32 partials

  dim3 blk(256);
  prep_kernel<<<640, blk, 0, stream>>>(qkv_w, proj_w, x, qkv_wf, proj_wf, stats);
  gn_apply<<<512, blk, 0, stream>>>(x, gn_w, gn_b, stats, xn);
  qkv_gemm<<<dim3(32, 6, 2), dim3(512), 0, stream>>>(xn, qkv_wf, qkv_b, qbuf, kg, vg);
  attn_kernel<<<dim3(1024), dim3(512), 0, stream>>>(qbuf, kg, vg, attn_t);
  proj_gemm<<<dim3(64, 4, 2), blk, 0, stream>>>(attn_t, proj_wf, proj_b, x, out);
}